// Round 5
// baseline (36.582 us; speedup 1.0000x reference)
//
#include <hip/hip_runtime.h>

// NGramsEmbedding: out[t, :] = sum_{n=0..2} W[idx[n, t], :]
//   idx: [3, T] int32, W: [50257, 256] f32, out: [T, 256] f32
//
// R5: 256B column slices (discriminating probe vs R4's 128B).
//   4 slices of 64 floats. XCD x (= blockIdx&7) handles slice x&3 for token
//   half x>>2. Per-XCD L2 working set doubles to 12.8 MB (reuse loss risk),
//   but write bursts double to 256B (HBM write-efficiency gain if R4 was
//   write-burst-bound). Each wave: 4 tokens per instruction (16 lanes x 16B
//   = one 256B slice), 16 tokens per wave, 12 gathers + 4 NT stores.

typedef float f32x4 __attribute__((ext_vector_type(4)));

__global__ __launch_bounds__(256) void ngrams_embed_slice256_kernel(
    const int* __restrict__ idx,
    const float* __restrict__ weight,
    float* __restrict__ out,
    int T)
{
    const int xcd   = blockIdx.x & 7;          // XCD id under round-robin dispatch
    const int tblk  = blockIdx.x >> 3;         // 128-token block
    const int slice = xcd & 3;                 // 256B column slice (64 floats)
    const int thalf = xcd >> 2;                // which 64-token half of the block
    const int wave  = threadIdx.x >> 6;        // 0..3
    const int lane  = threadIdx.x & 63;
    const int sub   = lane >> 4;               // token-within-group 0..3
    const int cpart = lane & 15;               // 16B chunk within 256B slice

    const int base = tblk * 128 + thalf * 64 + wave * 16;  // 16 tokens per wave

    // 12 indices per lane (16-fold redundant across lanes -> broadcast)
    int rows[4][3];
#pragma unroll
    for (int g = 0; g < 4; ++g) {
        const int tk = base + g * 4 + sub;
#pragma unroll
        for (int n = 0; n < 3; ++n)
            rows[g][n] = idx[n * T + tk];
    }

    // 12 independent 16B gathers (4 scattered 256B segments per wave instr)
    const float* wbase = weight + slice * 64 + cpart * 4;
    f32x4 v[4][3];
#pragma unroll
    for (int g = 0; g < 4; ++g)
#pragma unroll
        for (int n = 0; n < 3; ++n)
            v[g][n] = *reinterpret_cast<const f32x4*>(wbase + (long long)rows[g][n] * 256);

#pragma unroll
    for (int g = 0; g < 4; ++g) {
        const int tk = base + g * 4 + sub;
        const f32x4 s = v[g][0] + v[g][1] + v[g][2];
        f32x4* dst = reinterpret_cast<f32x4*>(out + (long long)tk * 256 + slice * 64 + cpart * 4);
        __builtin_nontemporal_store(s, dst);
    }
}

extern "C" void kernel_launch(void* const* d_in, const int* in_sizes, int n_in,
                              void* d_out, int out_size, void* d_ws, size_t ws_size,
                              hipStream_t stream) {
    const int*   idx    = (const int*)d_in[0];    // [3, seq, batch] flattened
    const float* weight = (const float*)d_in[1];  // [V, 256]
    float*       out    = (float*)d_out;          // [seq, batch, 256]

    const int T = in_sizes[0] / 3;                // tokens = 65536 (mult of 128)

    const int block = 256;
    const int grid  = (T / 128) * 8;              // 8 XCD-blocks per 128 tokens
    ngrams_embed_slice256_kernel<<<grid, block, 0, stream>>>(idx, weight, out, T);
}

// Round 6
// 31.150 us; speedup vs baseline: 1.1744x; 1.1744x over previous
//
#include <hip/hip_runtime.h>

// NGramsEmbedding: out[t, :] = sum_{n=0..2} W[idx[n, t], :]
//   idx: [3, T] int32, W: [50257, 256] f32, out: [T, 256] f32
//
// R6: R4's 128B XCD column slices + sequentialized per-wave token walk.
//   Read structure identical to R4 (FETCH was compulsory-minimal 49.6 MB).
//   Change: each wave owns 128 CONTIGUOUS tokens and processes them in 4
//   sequential 32-token iterations -> 4x fewer concurrent write streams per
//   XCD, each advancing through memory in order (better DRAM page locality
//   for the stride-1KB 128B write pattern). Grid 1024 blocks (128 tblk x 8).

typedef float f32x4 __attribute__((ext_vector_type(4)));

__global__ __launch_bounds__(256) void ngrams_embed_seq_kernel(
    const int* __restrict__ idx,
    const float* __restrict__ weight,
    float* __restrict__ out,
    int T)
{
    const int slice = blockIdx.x & 7;          // XCD id under round-robin dispatch
    const int tblk  = blockIdx.x >> 3;         // 512-token block
    const int wave  = threadIdx.x >> 6;        // 0..3
    const int lane  = threadIdx.x & 63;
    const int sub   = lane >> 3;               // token-within-group 0..7
    const int cpart = lane & 7;                // 16B chunk within 128B slice

    const float* wbase = weight + slice * 32 + cpart * 4;
    const int wtok0 = tblk * 512 + wave * 128; // this wave's 128 contiguous tokens

#pragma unroll
    for (int it = 0; it < 4; ++it) {
        const int tw = wtok0 + it * 32;

        int rows[4][3];
#pragma unroll
        for (int g = 0; g < 4; ++g) {
            const int tk = tw + g * 8 + sub;
#pragma unroll
            for (int n = 0; n < 3; ++n)
                rows[g][n] = idx[n * T + tk];
        }

        f32x4 v[4][3];
#pragma unroll
        for (int g = 0; g < 4; ++g)
#pragma unroll
            for (int n = 0; n < 3; ++n)
                v[g][n] = *reinterpret_cast<const f32x4*>(wbase + (long long)rows[g][n] * 256);

#pragma unroll
        for (int g = 0; g < 4; ++g) {
            const int tk = tw + g * 8 + sub;
            const f32x4 s = v[g][0] + v[g][1] + v[g][2];
            f32x4* dst = reinterpret_cast<f32x4*>(out + (long long)tk * 256 + slice * 32 + cpart * 4);
            __builtin_nontemporal_store(s, dst);
        }
    }
}

extern "C" void kernel_launch(void* const* d_in, const int* in_sizes, int n_in,
                              void* d_out, int out_size, void* d_ws, size_t ws_size,
                              hipStream_t stream) {
    const int*   idx    = (const int*)d_in[0];    // [3, seq, batch] flattened
    const float* weight = (const float*)d_in[1];  // [V, 256]
    float*       out    = (float*)d_out;          // [seq, batch, 256]

    const int T = in_sizes[0] / 3;                // tokens = 65536 (mult of 512)

    const int block = 256;
    const int grid  = (T / 512) * 8;              // 128 tblks x 8 slices = 1024
    ngrams_embed_seq_kernel<<<grid, block, 0, stream>>>(idx, weight, out, T);
}